// Round 1
// baseline (1436.201 us; speedup 1.0000x reference)
//
#include <hip/hip_runtime.h>
#include <hip/hip_bf16.h>
#include <cstdint>

#define MB 8
#define TT 2048
#define DIMK 1024
#define CC 128
#define GG 16
#define MROWS (MB*TT)   /* 16384 */
#define NPROJ 576
#define YSTR 576

// ---------------------------------------------------------------------------
// Pack weights: Wcat[k][n] n in [0,576): 0-127 Wq, 128-255 Wk, 256-383 Wv,
// 384-511 Wg, 512 Wa, 513 Wb, rest 0.
// ---------------------------------------------------------------------------
__global__ void pack_w(const float* __restrict__ Wq, const float* __restrict__ Wk,
                       const float* __restrict__ Wv, const float* __restrict__ Wg,
                       const float* __restrict__ Wa, const float* __restrict__ Wb,
                       float* __restrict__ Wcat)
{
    int idx = blockIdx.x * 256 + threadIdx.x;
    if (idx >= DIMK * NPROJ) return;
    int k = idx / NPROJ, n = idx % NPROJ;
    float v = 0.f;
    if      (n < 128) v = Wq[k * 128 + n];
    else if (n < 256) v = Wk[k * 128 + (n - 128)];
    else if (n < 384) v = Wv[k * 128 + (n - 256)];
    else if (n < 512) v = Wg[k * 128 + (n - 384)];
    else if (n == 512) v = Wa[k];
    else if (n == 513) v = Wb[k];
    Wcat[idx] = v;
}

__global__ void pack_bias(const float* __restrict__ bq, const float* __restrict__ bk,
                          const float* __restrict__ bv, const float* __restrict__ bg,
                          const float* __restrict__ ba, const float* __restrict__ bb,
                          float* __restrict__ biascat)
{
    int n = threadIdx.x;
    if (n >= NPROJ) return;
    float v = 0.f;
    if      (n < 128) v = bq[n];
    else if (n < 256) v = bk[n - 128];
    else if (n < 384) v = bv[n - 256];
    else if (n < 512) v = bg[n - 384];
    else if (n == 512) v = ba[0];
    else if (n == 513) v = bb[0];
    biascat[n] = v;
}

// ---------------------------------------------------------------------------
// Tiled fp32 SGEMM: C[M][N] = A[M][K] @ B[K][N] + bias[N]
// Tile 128(M) x 64(N), BK=16, 256 threads, 8x4 per thread.
// Requires M%128==0, N%64==0, K%16==0.
// ---------------------------------------------------------------------------
__global__ __launch_bounds__(256) void sgemm_bias(
    const float* __restrict__ A, const float* __restrict__ Bm,
    const float* __restrict__ bias, float* __restrict__ Cm,
    int M, int N, int K)
{
    __shared__ float As[16][128];
    __shared__ float Bs[16][64];
    int tid = threadIdx.x;
    int bm = blockIdx.y * 128;
    int bn = blockIdx.x * 64;
    int tx = tid & 15, ty = tid >> 4;
    float acc[8][4];
#pragma unroll
    for (int u = 0; u < 8; u++)
#pragma unroll
        for (int w = 0; w < 4; w++) acc[u][w] = 0.f;

    for (int kk = 0; kk < K; kk += 16) {
        // stage A tile (128x16), k-major in LDS
#pragma unroll
        for (int j = 0; j < 2; j++) {
            int fid = tid * 2 + j;
            int row = fid >> 2, kq = fid & 3;
            const float4 av = *(const float4*)(A + (size_t)(bm + row) * K + kk + kq * 4);
            As[kq * 4 + 0][row] = av.x;
            As[kq * 4 + 1][row] = av.y;
            As[kq * 4 + 2][row] = av.z;
            As[kq * 4 + 3][row] = av.w;
        }
        // stage B tile (16x64)
        {
            int krow = tid >> 4, c4 = tid & 15;
            const float4 bv = *(const float4*)(Bm + (size_t)(kk + krow) * N + bn + c4 * 4);
            *(float4*)&Bs[krow][c4 * 4] = bv;
        }
        __syncthreads();
#pragma unroll
        for (int kc = 0; kc < 16; kc++) {
            float4 a0 = *(const float4*)&As[kc][ty * 8];
            float4 a1 = *(const float4*)&As[kc][ty * 8 + 4];
            float4 bv = *(const float4*)&Bs[kc][tx * 4];
            float av[8] = {a0.x, a0.y, a0.z, a0.w, a1.x, a1.y, a1.z, a1.w};
            float bw[4] = {bv.x, bv.y, bv.z, bv.w};
#pragma unroll
            for (int u = 0; u < 8; u++)
#pragma unroll
                for (int w = 0; w < 4; w++)
                    acc[u][w] += av[u] * bw[w];
        }
        __syncthreads();
    }
    float4 b4 = *(const float4*)(bias + bn + tx * 4);
#pragma unroll
    for (int u = 0; u < 8; u++) {
        float4 r = make_float4(acc[u][0] + b4.x, acc[u][1] + b4.y,
                               acc[u][2] + b4.z, acc[u][3] + b4.w);
        *(float4*)(Cm + (size_t)(bm + ty * 8 + u) * N + bn + tx * 4) = r;
    }
}

// ---------------------------------------------------------------------------
// Post-projection elementwise: k row-normalize, sigmoid(g), sigmoid(a,b).
// One wave per row m.
// ---------------------------------------------------------------------------
__global__ __launch_bounds__(64) void postproj_kernel(
    const float* __restrict__ Y, float* __restrict__ knorm,
    float* __restrict__ gbuf, float* __restrict__ alpha, float* __restrict__ beta)
{
    int m = blockIdx.x;
    int lane = threadIdx.x;
    const float* yr = Y + (size_t)m * YSTR;
    float k0 = yr[128 + lane], k1 = yr[192 + lane];
    float ss = k0 * k0 + k1 * k1;
#pragma unroll
    for (int mask = 1; mask < 64; mask <<= 1) ss += __shfl_xor(ss, mask);
    float inv = 1.0f / fmaxf(sqrtf(ss), 1e-12f);
    knorm[(size_t)m * CC + lane]      = k0 * inv;
    knorm[(size_t)m * CC + 64 + lane] = k1 * inv;
    float g0 = yr[384 + lane], g1 = yr[448 + lane];
    gbuf[(size_t)m * CC + lane]      = 1.f / (1.f + expf(-g0));
    gbuf[(size_t)m * CC + 64 + lane] = 1.f / (1.f + expf(-g1));
    if (lane == 0) {
        alpha[m] = 1.f / (1.f + expf(-yr[512]));
        beta[m]  = 1.f / (1.f + expf(-yr[513]));
    }
}

// ---------------------------------------------------------------------------
// Sequential scan. Grid = MB*GG blocks of 1 wave. Block (b,gi) owns rows
// [gi*8, gi*8+8) of state S for batch b. Lane layout: jg=lane&15 (8 cols each),
// ig=lane>>4 (2 rows each). State in registers.
// Writes per-group partial o (pre-gate) either as packed bf16 (big-ws path)
// or atomicAdd fp32 (small-ws path).
// ---------------------------------------------------------------------------
template <bool ATOMIC>
__global__ __launch_bounds__(64) void scan_kernel(
    const float* __restrict__ Y, const float* __restrict__ knorm,
    const float* __restrict__ alpha, const float* __restrict__ beta,
    void* __restrict__ outp)
{
    int blk = blockIdx.x;
    int b = blk >> 4;
    int gi = blk & 15;
    int lane = threadIdx.x;
    int jg = lane & 15, ig = lane >> 4;
    int i0 = gi * 8 + ig * 2, i1 = i0 + 1;
    float s0[8], s1[8];
#pragma unroll
    for (int c = 0; c < 8; c++) { s0[c] = 0.f; s1[c] = 0.f; }
    size_t mbase = (size_t)b * TT;

    float4 ka, kb;
    float q0, q1, v0, v1, at, bt;
    {
        const float* kr = knorm + mbase * CC + jg * 8;
        ka = *(const float4*)kr; kb = *(const float4*)(kr + 4);
        const float* yr = Y + mbase * YSTR;
        q0 = yr[i0]; q1 = yr[i1]; v0 = yr[256 + i0]; v1 = yr[256 + i1];
        at = alpha[mbase]; bt = beta[mbase];
    }

    for (int t = 0; t < TT; ++t) {
        // prefetch next step's inputs (clamped at the end; harmless reload)
        int tn = (t + 1 < TT) ? t + 1 : t;
        size_t mn = mbase + tn;
        const float* krn = knorm + mn * CC + jg * 8;
        float4 kan = *(const float4*)krn;
        float4 kbn = *(const float4*)(krn + 4);
        const float* yrn = Y + mn * YSTR;
        float q0n = yrn[i0], q1n = yrn[i1];
        float v0n = yrn[256 + i0], v1n = yrn[256 + i1];
        float atn = alpha[mn], btn = beta[mn];

        float k[8] = {ka.x, ka.y, ka.z, ka.w, kb.x, kb.y, kb.z, kb.w};
        // Sk_i = S[i,:] . k   (reduce over 16 j-lanes)
        float p0 = 0.f, p1 = 0.f;
#pragma unroll
        for (int c = 0; c < 8; c++) { p0 += s0[c] * k[c]; p1 += s1[c] * k[c]; }
#pragma unroll
        for (int mask = 1; mask < 16; mask <<= 1) {
            p0 += __shfl_xor(p0, mask);
            p1 += __shfl_xor(p1, mask);
        }
        float c0 = bt * (v0 - at * p0);
        float c1 = bt * (v1 - at * p1);
        float po[8];
#pragma unroll
        for (int c = 0; c < 8; c++) {
            s0[c] = at * s0[c] + c0 * k[c];
            s1[c] = at * s1[c] + c1 * k[c];
            po[c] = q0 * s0[c] + q1 * s1[c];
        }
        // reduce o-partial over the 4 i-groups (off critical path)
#pragma unroll
        for (int c = 0; c < 8; c++) {
            po[c] += __shfl_xor(po[c], 16);
            po[c] += __shfl_xor(po[c], 32);
        }
        size_t m = mbase + t;
        if (ATOMIC) {
            if (ig == 0) {
                float* op = (float*)outp + m * CC + jg * 8;
#pragma unroll
                for (int c = 0; c < 8; c++) atomicAdd(op + c, po[c]);
            }
        } else {
            if (ig == 0) {
                unsigned pk[4];
#pragma unroll
                for (int c = 0; c < 4; c++) {
                    unsigned ux = __float_as_uint(po[2 * c]);
                    ux += 0x7fffu + ((ux >> 16) & 1u);
                    unsigned uy = __float_as_uint(po[2 * c + 1]);
                    uy += 0x7fffu + ((uy >> 16) & 1u);
                    pk[c] = (ux >> 16) | (uy & 0xffff0000u);
                }
                unsigned* op = (unsigned*)outp + ((size_t)gi * MROWS + m) * 64 + jg * 4;
                *(uint4*)op = make_uint4(pk[0], pk[1], pk[2], pk[3]);
            }
        }
        ka = kan; kb = kbn; q0 = q0n; q1 = q1n; v0 = v0n; v1 = v1n; at = atn; bt = btn;
    }
}

// ---------------------------------------------------------------------------
// Combine bf16 partials over G groups, apply gate.
// ---------------------------------------------------------------------------
__global__ __launch_bounds__(256) void combine_kernel(
    const unsigned short* __restrict__ opart,
    const float* __restrict__ gbuf, float* __restrict__ ocomb)
{
    size_t idx = (size_t)blockIdx.x * 256 + threadIdx.x;  // < MROWS*CC
    float s = 0.f;
#pragma unroll
    for (int gi = 0; gi < GG; ++gi) {
        unsigned u = opart[(size_t)gi * MROWS * CC + idx];
        s += __uint_as_float(u << 16);
    }
    ocomb[idx] = s * gbuf[idx];
}

__global__ __launch_bounds__(256) void gate_kernel(
    float* __restrict__ ocomb, const float* __restrict__ gbuf)
{
    size_t idx = (size_t)blockIdx.x * 256 + threadIdx.x;
    ocomb[idx] *= gbuf[idx];
}

// ---------------------------------------------------------------------------
extern "C" void kernel_launch(void* const* d_in, const int* in_sizes, int n_in,
                              void* d_out, int out_size, void* d_ws, size_t ws_size,
                              hipStream_t stream)
{
    const float* x  = (const float*)d_in[0];
    const float* Wq = (const float*)d_in[1];
    const float* bq = (const float*)d_in[2];
    const float* Wk = (const float*)d_in[3];
    const float* bk = (const float*)d_in[4];
    const float* Wv = (const float*)d_in[5];
    const float* bv = (const float*)d_in[6];
    const float* Wa = (const float*)d_in[7];
    const float* ba = (const float*)d_in[8];
    const float* Wb = (const float*)d_in[9];
    const float* bb = (const float*)d_in[10];
    const float* Wg = (const float*)d_in[11];
    const float* bg = (const float*)d_in[12];
    const float* Wo = (const float*)d_in[13];
    const float* bo = (const float*)d_in[14];
    float* out = (float*)d_out;

    float* ws = (float*)d_ws;
    size_t off = 0;
    float* Wcat   = ws + off; off += (size_t)DIMK * NPROJ;
    float* biascat = ws + off; off += NPROJ;
    off = (off + 3) & ~(size_t)3;
    float* Y     = ws + off; off += (size_t)MROWS * YSTR;
    float* knorm = ws + off; off += (size_t)MROWS * CC;
    float* gbuf  = ws + off; off += (size_t)MROWS * CC;
    float* alpha = ws + off; off += MROWS;
    float* beta  = ws + off; off += MROWS;
    float* ocomb = ws + off; off += (size_t)MROWS * CC;
    unsigned short* opart = (unsigned short*)(ws + off);
    size_t need_big = (off + (size_t)GG * MROWS * CC / 2) * sizeof(float);
    bool big = ws_size >= need_big;

    hipLaunchKernelGGL(pack_w, dim3((DIMK * NPROJ + 255) / 256), dim3(256), 0, stream,
                       Wq, Wk, Wv, Wg, Wa, Wb, Wcat);
    hipLaunchKernelGGL(pack_bias, dim3(1), dim3(NPROJ), 0, stream,
                       bq, bk, bv, bg, ba, bb, biascat);
    hipLaunchKernelGGL(sgemm_bias, dim3(NPROJ / 64, MROWS / 128), dim3(256), 0, stream,
                       x, Wcat, biascat, Y, MROWS, NPROJ, DIMK);
    hipLaunchKernelGGL(postproj_kernel, dim3(MROWS), dim3(64), 0, stream,
                       Y, knorm, gbuf, alpha, beta);
    if (big) {
        hipLaunchKernelGGL((scan_kernel<false>), dim3(MB * GG), dim3(64), 0, stream,
                           Y, knorm, alpha, beta, (void*)opart);
        hipLaunchKernelGGL(combine_kernel, dim3(MROWS * CC / 256), dim3(256), 0, stream,
                           opart, gbuf, ocomb);
    } else {
        hipMemsetAsync(ocomb, 0, (size_t)MROWS * CC * sizeof(float), stream);
        hipLaunchKernelGGL((scan_kernel<true>), dim3(MB * GG), dim3(64), 0, stream,
                           Y, knorm, alpha, beta, (void*)ocomb);
        hipLaunchKernelGGL(gate_kernel, dim3(MROWS * CC / 256), dim3(256), 0, stream,
                           ocomb, gbuf);
    }
    hipLaunchKernelGGL(sgemm_bias, dim3(DIMK / 64, MROWS / 128), dim3(256), 0, stream,
                       ocomb, Wo, bo, out, MROWS, DIMK, CC);
}